// Round 1
// 1783.228 us; speedup vs baseline: 1.0393x; 1.0393x over previous
//
#include <hip/hip_runtime.h>
#include <hip/hip_bf16.h>

// ---------------------------------------------------------------------------
// CANDY_41077067219071: out = p_out + z_out where
//   t     = Wp_eff @ (x * act(p_mask))          (per channel, 1024^3)
//   p_out = act(act(t) @ p_lin_w^T + b_p)
//   z     = Wzp @ p_out
//   z_out = act(act(z) @ z_lin_w^T + b_z)
// act(v) = clamp(v,-1,1).
// Round-2 rewrite: GEMMs moved from 128^2/2-barrier (m97 structure, ~860 TF
// ceiling, MfmaUtil 38%) to 256^2-tile BK=32 multi-phase schedule:
//   - 512 threads, 8 waves (2M x 4N), 128x64 per wave, acc[8][4]
//   - double-buffered LDS (split: 4 ops x 2 = 128 KiB; plain: 64 KiB)
//   - 4 phases per K-tile (one C-quadrant each): ds_read -> stage-issue ->
//     raw s_barrier -> setprio(1) MFMA cluster setprio(0) -> sched_barrier(0)
//     -> raw s_barrier
//   - counted s_waitcnt vmcnt(2) ONCE per K-tile (loads span phases); no
//     __syncthreads in the GEMM at all (avoids the vmcnt(0) drain).
// Numerics identical to round-1 kernel (same product order) -> absmax should
// stay 0.0234375 bit-identical.  OUTPUT IS FLOAT32.
// Workspace layout (needs ~652 MiB): unchanged from round 1.
// ---------------------------------------------------------------------------

typedef short bf16x8 __attribute__((ext_vector_type(8)));
typedef float f32x4  __attribute__((ext_vector_type(4)));

__device__ __forceinline__ float actf(float v) { return fminf(1.f, fmaxf(-1.f, v)); }

__device__ __forceinline__ unsigned short f2bf(float f) {
    union { __hip_bfloat16 b; unsigned short u; } cv;
    cv.b = __float2bfloat16(f);
    return cv.u;
}
__device__ __forceinline__ float bf2f(unsigned short u) {
    union { unsigned short u; __hip_bfloat16 b; } cv;
    cv.u = u;
    return __bfloat162float(cv.b);
}

// logical 16B chunk q of row r lives at physical chunk q ^ swz(r)
__device__ __forceinline__ int swz(int r) { return (r ^ (r >> 2)) & 3; }

__device__ __forceinline__ bf16x8 read_frag(const unsigned short* ldsBase, int row, int q) {
    const int pc = q ^ swz(row);
    return *(const bf16x8*)(ldsBase + row * 32 + pc * 8);
}

// EPI 0: O1 = bf16(act(acc))
// EPI 1: v = act(acc + bias[m]); O1 = hi(v), O2 = lo(v)
// EPI 2: v = act(acc + bias[m]) + (Phi+Plo)[off]; Of = v   (FLOAT32 store)
template <bool SPLIT, int EPI, bool TRIL>
__global__ __launch_bounds__(512, 2)
void gemm_tn8(const unsigned short* __restrict__ Ahi,
              const unsigned short* __restrict__ Alo,
              const unsigned short* __restrict__ Bhi,
              const unsigned short* __restrict__ Blo,
              const float* __restrict__ bias,
              const unsigned short* __restrict__ Phi,
              const unsigned short* __restrict__ Plo,
              unsigned short* __restrict__ O1,
              unsigned short* __restrict__ O2,
              float* __restrict__ Of) {
    constexpr int NOPS   = SPLIT ? 4 : 2;   // Ah,Bh[,Al,Bl]
    constexpr int ROUNDS = SPLIT ? 8 : 4;   // global_load_lds issues per K-tile per thread
    // one operand tile = 256 rows x 32 cols bf16 = 8192 elems (16 KiB)
    __shared__ __align__(16) unsigned short lds[NOPS * 2 * 8192];

    const int tid  = threadIdx.x;
    const int lane = tid & 63;
    const int wave = tid >> 6;          // 0..7
    const int wm = wave >> 2;           // 0..1  (M half)
    const int wn = wave & 3;            // 0..3  (N quarter)
    const int q  = lane >> 4;           // k-chunk 0..3
    const int mr = lane & 15;

    const int m0 = blockIdx.y * 256;
    const int n0 = blockIdx.x * 256;
    const size_t cb = (size_t)blockIdx.z << 20;   // per-channel offset (B/C/P only)

    const unsigned short* Bh = Bhi + cb;
    const unsigned short* Bl = SPLIT ? (Blo + cb) : nullptr;

    // stage one 8 KiB round (128 rows) of a 256x32 tile.  LDS dest is
    // wave-uniform base + lane*16 (HW rule); the XOR swizzle is applied on the
    // GLOBAL source address so LDS stays linear (both-sides-or-neither rule).
    auto stage1 = [&](const unsigned short* g, int row0, int k0,
                      unsigned short* base, int rnd) {
        const int ci = rnd * 512 + tid;       // chunk index 0..1023
        const int r  = ci >> 2;               // local row 0..255
        const int pc = ci & 3;                // physical chunk within row
        const int qq = pc ^ swz(r);           // logical chunk fetched from global
        const unsigned short* gsrc = g + ((size_t)(row0 + r) << 10) + k0 + qq * 8;
        unsigned short* ldst = base + (rnd * 512 + wave * 64) * 8;   // wave-uniform
        __builtin_amdgcn_global_load_lds((const __attribute__((address_space(1))) void*)gsrc,
                                         (__attribute__((address_space(3))) void*)ldst,
                                         16, 0, 0);
    };
    // idx is always a compile-time literal at call sites (unrolled contexts)
    auto issueRound = [&](int idx, int k0, int buf) {
        int op, rnd;
        if constexpr (SPLIT) { op = (idx & 1) + ((idx >= 4) ? 2 : 0); rnd = (idx >> 1) & 1; }
        else                 { op = idx & 1; rnd = idx >> 1; }
        const unsigned short* g; int row0;
        switch (op) {
            case 0:  g = Ahi; row0 = m0; break;
            case 1:  g = Bh;  row0 = n0; break;
            case 2:  g = Alo; row0 = m0; break;
            default: g = Bl;  row0 = n0; break;
        }
        stage1(g, row0, k0, lds + (op * 2 + buf) * 8192, rnd);
    };

    f32x4 acc[8][4];
#pragma unroll
    for (int i = 0; i < 8; ++i)
#pragma unroll
        for (int j = 0; j < 4; ++j) acc[i][j] = (f32x4){0.f, 0.f, 0.f, 0.f};

    // tril A: A[h,k]==0 for k>h; rows in this block are <= m0+255
    const int kEnd = TRIL ? ((m0 + 256 < 1024) ? m0 + 256 : 1024) : 1024;
    const int nt = kEnd >> 5;

    // prologue: stage tile 0 into buf 0
#pragma unroll
    for (int idx = 0; idx < ROUNDS; ++idx) issueRound(idx, 0, 0);

    for (int t = 0; t < nt; ++t) {
        const int cur = t & 1;
        const int nxt = cur ^ 1;
        const int k0n = (t + 1) << 5;
        const bool pf = (t + 1) < nt;

        const unsigned short* Ah_ = lds + (0 * 2 + cur) * 8192;
        const unsigned short* Bh_ = lds + (1 * 2 + cur) * 8192;
        const unsigned short* Al_ = SPLIT ? (lds + (2 * 2 + cur) * 8192) : nullptr;
        const unsigned short* Bl_ = SPLIT ? (lds + (3 * 2 + cur) * 8192) : nullptr;

        // ---- K-tile boundary: issue first prefetch rounds of t+1, then wait
        // (counted!) for tile t's loads; barrier makes them visible to all.
        if (pf) {
            issueRound(0, k0n, nxt);
            issueRound(1, k0n, nxt);
            asm volatile("s_waitcnt vmcnt(2)" ::: "memory");
        } else {
            asm volatile("s_waitcnt vmcnt(0)" ::: "memory");
        }
        asm volatile("s_barrier" ::: "memory");

        bf16x8 bh01[2], bl01[2], bh23[2], bl23[2];

        // ---- phase 0: quadrant i=0..3, j=0..1 (reads B j0-1) ----
        {
            bf16x8 aH[4], aL[4];
#pragma unroll
            for (int i = 0; i < 4; ++i) {
                aH[i] = read_frag(Ah_, wm * 128 + i * 16 + mr, q);
                if constexpr (SPLIT) aL[i] = read_frag(Al_, wm * 128 + i * 16 + mr, q);
            }
#pragma unroll
            for (int j = 0; j < 2; ++j) {
                bh01[j] = read_frag(Bh_, wn * 64 + j * 16 + mr, q);
                if constexpr (SPLIT) bl01[j] = read_frag(Bl_, wn * 64 + j * 16 + mr, q);
            }
            if (pf) { issueRound(2, k0n, nxt); issueRound(3, k0n, nxt); }
            asm volatile("s_barrier" ::: "memory");
            __builtin_amdgcn_s_setprio(1);
#pragma unroll
            for (int i = 0; i < 4; ++i)
#pragma unroll
                for (int j = 0; j < 2; ++j) {
                    if constexpr (SPLIT) {
                        acc[i][j] = __builtin_amdgcn_mfma_f32_16x16x32_bf16(aL[i], bh01[j], acc[i][j], 0, 0, 0);
                        acc[i][j] = __builtin_amdgcn_mfma_f32_16x16x32_bf16(aH[i], bl01[j], acc[i][j], 0, 0, 0);
                    }
                    acc[i][j] = __builtin_amdgcn_mfma_f32_16x16x32_bf16(aH[i], bh01[j], acc[i][j], 0, 0, 0);
                }
            __builtin_amdgcn_s_setprio(0);
            __builtin_amdgcn_sched_barrier(0);
            asm volatile("s_barrier" ::: "memory");
        }

        // ---- phase 1: quadrant i=4..7, j=0..1 ----
        {
            bf16x8 aH[4], aL[4];
#pragma unroll
            for (int i = 0; i < 4; ++i) {
                aH[i] = read_frag(Ah_, wm * 128 + 64 + i * 16 + mr, q);
                if constexpr (SPLIT) aL[i] = read_frag(Al_, wm * 128 + 64 + i * 16 + mr, q);
            }
            if constexpr (SPLIT) {
                if (pf) { issueRound(4, k0n, nxt); issueRound(5, k0n, nxt); }
            }
            asm volatile("s_barrier" ::: "memory");
            __builtin_amdgcn_s_setprio(1);
#pragma unroll
            for (int i = 0; i < 4; ++i)
#pragma unroll
                for (int j = 0; j < 2; ++j) {
                    if constexpr (SPLIT) {
                        acc[i + 4][j] = __builtin_amdgcn_mfma_f32_16x16x32_bf16(aL[i], bh01[j], acc[i + 4][j], 0, 0, 0);
                        acc[i + 4][j] = __builtin_amdgcn_mfma_f32_16x16x32_bf16(aH[i], bl01[j], acc[i + 4][j], 0, 0, 0);
                    }
                    acc[i + 4][j] = __builtin_amdgcn_mfma_f32_16x16x32_bf16(aH[i], bh01[j], acc[i + 4][j], 0, 0, 0);
                }
            __builtin_amdgcn_s_setprio(0);
            __builtin_amdgcn_sched_barrier(0);
            asm volatile("s_barrier" ::: "memory");
        }

        // ---- phase 2: quadrant i=0..3, j=2..3 (reads B j2-3) ----
        {
            bf16x8 aH[4], aL[4];
#pragma unroll
            for (int i = 0; i < 4; ++i) {
                aH[i] = read_frag(Ah_, wm * 128 + i * 16 + mr, q);
                if constexpr (SPLIT) aL[i] = read_frag(Al_, wm * 128 + i * 16 + mr, q);
            }
#pragma unroll
            for (int j = 0; j < 2; ++j) {
                bh23[j] = read_frag(Bh_, wn * 64 + (j + 2) * 16 + mr, q);
                if constexpr (SPLIT) bl23[j] = read_frag(Bl_, wn * 64 + (j + 2) * 16 + mr, q);
            }
            if constexpr (SPLIT) {
                if (pf) { issueRound(6, k0n, nxt); issueRound(7, k0n, nxt); }
            }
            asm volatile("s_barrier" ::: "memory");
            __builtin_amdgcn_s_setprio(1);
#pragma unroll
            for (int i = 0; i < 4; ++i)
#pragma unroll
                for (int j = 0; j < 2; ++j) {
                    if constexpr (SPLIT) {
                        acc[i][j + 2] = __builtin_amdgcn_mfma_f32_16x16x32_bf16(aL[i], bh23[j], acc[i][j + 2], 0, 0, 0);
                        acc[i][j + 2] = __builtin_amdgcn_mfma_f32_16x16x32_bf16(aH[i], bl23[j], acc[i][j + 2], 0, 0, 0);
                    }
                    acc[i][j + 2] = __builtin_amdgcn_mfma_f32_16x16x32_bf16(aH[i], bh23[j], acc[i][j + 2], 0, 0, 0);
                }
            __builtin_amdgcn_s_setprio(0);
            __builtin_amdgcn_sched_barrier(0);
            asm volatile("s_barrier" ::: "memory");
        }

        // ---- phase 3: quadrant i=4..7, j=2..3 ----
        {
            bf16x8 aH[4], aL[4];
#pragma unroll
            for (int i = 0; i < 4; ++i) {
                aH[i] = read_frag(Ah_, wm * 128 + 64 + i * 16 + mr, q);
                if constexpr (SPLIT) aL[i] = read_frag(Al_, wm * 128 + 64 + i * 16 + mr, q);
            }
            asm volatile("s_barrier" ::: "memory");
            __builtin_amdgcn_s_setprio(1);
#pragma unroll
            for (int i = 0; i < 4; ++i)
#pragma unroll
                for (int j = 0; j < 2; ++j) {
                    if constexpr (SPLIT) {
                        acc[i + 4][j + 2] = __builtin_amdgcn_mfma_f32_16x16x32_bf16(aL[i], bh23[j], acc[i + 4][j + 2], 0, 0, 0);
                        acc[i + 4][j + 2] = __builtin_amdgcn_mfma_f32_16x16x32_bf16(aH[i], bl23[j], acc[i + 4][j + 2], 0, 0, 0);
                    }
                    acc[i + 4][j + 2] = __builtin_amdgcn_mfma_f32_16x16x32_bf16(aH[i], bh23[j], acc[i + 4][j + 2], 0, 0, 0);
                }
            __builtin_amdgcn_s_setprio(0);
            __builtin_amdgcn_sched_barrier(0);
            asm volatile("s_barrier" ::: "memory");
        }
    }

    // C/D layout (m89/m91-verified): col = lane&15, row = (lane>>4)*4 + reg
#pragma unroll
    for (int i = 0; i < 8; ++i) {
        const int gmBase = m0 + wm * 128 + i * 16 + q * 4;
#pragma unroll
        for (int j = 0; j < 4; ++j) {
            const int gn = n0 + wn * 64 + j * 16 + mr;
#pragma unroll
            for (int r4 = 0; r4 < 4; ++r4) {
                const int gm = gmBase + r4;
                const size_t off = cb + ((size_t)gm << 10) + gn;
                float v = acc[i][j][r4];
                if constexpr (EPI == 0) {
                    O1[off] = f2bf(actf(v));
                } else if constexpr (EPI == 1) {
                    v = actf(v + bias[gm]);
                    const unsigned short hi = f2bf(v);
                    O1[off] = hi;
                    O2[off] = f2bf(v - bf2f(hi));
                } else {
                    v = actf(v + bias[gm]);
                    v += bf2f(Phi[off]) + bf2f(Plo[off]);
                    Of[off] = v;                      // float32 store
                }
            }
        }
    }
}

// Wp_eff = tril(Wp) with diag -> clamp(diag,0,1) + Wp_diag; split hi/lo.
// Wzp split hi/lo.  p_lin_w / z_lin_w plain bf16 (layout [j][i], K-contig).
__global__ void prep_weights(const float* __restrict__ Wp, const float* __restrict__ Wpd,
                             const float* __restrict__ Wzp,
                             const float* __restrict__ plw, const float* __restrict__ zlw,
                             unsigned short* __restrict__ WpHi, unsigned short* __restrict__ WpLo,
                             unsigned short* __restrict__ WzHi, unsigned short* __restrict__ WzLo,
                             unsigned short* __restrict__ plw16, unsigned short* __restrict__ zlw16) {
    const int idx = blockIdx.x * 256 + threadIdx.x;   // 0..1M-1
    const int h = idx >> 10, k = idx & 1023;
    float v = (k < h) ? Wp[idx] : 0.f;
    if (k == h) v = fminf(1.f, fmaxf(0.f, Wp[idx])) + Wpd[h];
    unsigned short hi = f2bf(v);
    WpHi[idx] = hi; WpLo[idx] = f2bf(v - bf2f(hi));
    const float wz = Wzp[idx];
    hi = f2bf(wz);
    WzHi[idx] = hi; WzLo[idx] = f2bf(wz - bf2f(hi));
    plw16[idx] = f2bf(plw[idx]);
    zlw16[idx] = f2bf(zlw[idx]);
}

// pSetT[c][i][h] = x[c][h][i] * act(p_mask[h][i]), split hi/lo. LDS-tiled transpose.
__global__ void prep_pset(const float* __restrict__ x, const float* __restrict__ pmask,
                          unsigned short* __restrict__ Thi, unsigned short* __restrict__ Tlo) {
    __shared__ float tile[32][33];
    const int tx = threadIdx.x, ty = threadIdx.y;     // 32 x 8
    const int i0 = blockIdx.x * 32, h0 = blockIdx.y * 32;
    const size_t cb = (size_t)blockIdx.z << 20;
#pragma unroll
    for (int s = 0; s < 4; ++s) {
        const int hh = ty + s * 8;
        const size_t gi = ((size_t)(h0 + hh) << 10) + i0 + tx;
        tile[hh][tx] = x[cb + gi] * actf(pmask[gi]);
    }
    __syncthreads();
#pragma unroll
    for (int s = 0; s < 4; ++s) {
        const int ii = ty + s * 8;
        const float v = tile[tx][ii];
        const size_t go = cb + ((size_t)(i0 + ii) << 10) + h0 + tx;
        const unsigned short hi = f2bf(v);
        Thi[go] = hi;
        Tlo[go] = f2bf(v - bf2f(hi));
    }
}

// out[c][h][j] = inT[c][j][h]  (float32)
__global__ void transpose_out(const float* __restrict__ inT,
                              float* __restrict__ out) {
    __shared__ float tile[32][33];
    const int tx = threadIdx.x, ty = threadIdx.y;     // 32 x 8
    const int h0 = blockIdx.x * 32, j0 = blockIdx.y * 32;
    const size_t cb = (size_t)blockIdx.z << 20;
#pragma unroll
    for (int s = 0; s < 4; ++s) {
        const int jj = ty + s * 8;
        tile[jj][tx] = inT[cb + ((size_t)(j0 + jj) << 10) + h0 + tx];
    }
    __syncthreads();
#pragma unroll
    for (int s = 0; s < 4; ++s) {
        const int hh = ty + s * 8;
        out[cb + ((size_t)(h0 + hh) << 10) + j0 + tx] = tile[tx][hh];
    }
}

extern "C" void kernel_launch(void* const* d_in, const int* in_sizes, int n_in,
                              void* d_out, int out_size, void* d_ws, size_t ws_size,
                              hipStream_t stream) {
    const float* x     = (const float*)d_in[0];
    const float* pmask = (const float*)d_in[1];
    const float* Wp    = (const float*)d_in[2];
    const float* Wpd   = (const float*)d_in[3];
    const float* Wzp   = (const float*)d_in[4];
    const float* plw   = (const float*)d_in[5];
    const float* plb   = (const float*)d_in[6];
    const float* zlw   = (const float*)d_in[7];
    const float* zlb   = (const float*)d_in[8];
    float* out = (float*)d_out;                     // FLOAT32 output

    char* w = (char*)d_ws;
    const size_t SZ = 134217728ull;                 // 64*1024*1024 bf16 = 128 MiB
    unsigned short* pSetT_hi = (unsigned short*)(w);
    unsigned short* pSetT_lo = (unsigned short*)(w + SZ);
    unsigned short* pT_hi    = (unsigned short*)(w + 2 * SZ);
    unsigned short* pT_lo    = (unsigned short*)(w + 3 * SZ);
    unsigned short* tA       = (unsigned short*)(w + 4 * SZ);  // act_t; reused as act_z
    float*          outT     = (float*)(w);                    // f32, reuses pSetT hi+lo (256 MiB)
    unsigned short* wts      = (unsigned short*)(w + 5 * SZ);
    unsigned short* WpHi = wts;
    unsigned short* WpLo = wts + 1 * 1048576;
    unsigned short* WzHi = wts + 2 * 1048576;
    unsigned short* WzLo = wts + 3 * 1048576;
    unsigned short* plw16 = wts + 4 * 1048576;
    unsigned short* zlw16 = wts + 5 * 1048576;

    const dim3 gW(4096), bW(256);
    const dim3 gT(32, 32, 64), bT(32, 8);
    const dim3 gG(4, 4, 64), bG(512);

    prep_weights<<<gW, bW, 0, stream>>>(Wp, Wpd, Wzp, plw, zlw,
                                        WpHi, WpLo, WzHi, WzLo, plw16, zlw16);
    prep_pset<<<gT, bT, 0, stream>>>(x, pmask, pSetT_hi, pSetT_lo);

    // mm1: act_t[c][h][i] = act( sum_k Wp_eff[h,k] * pSetT[c][i][k] )   [split, tril]
    gemm_tn8<true, 0, true><<<gG, bG, 0, stream>>>(
        WpHi, WpLo, pSetT_hi, pSetT_lo, nullptr, nullptr, nullptr, tA, nullptr, nullptr);

    // mm2 (transposed): pT[c][j][h] = act( sum_i plw[j,i] * act_t[c][h][i] + b_p[j] ), split store
    gemm_tn8<false, 1, false><<<gG, bG, 0, stream>>>(
        plw16, nullptr, tA, nullptr, plb, nullptr, nullptr, pT_hi, pT_lo, nullptr);

    // mm3: act_z[c][h][i] = act( sum_k Wzp[h,k] * pT[c][i][k] )   [split]
    gemm_tn8<true, 0, false><<<gG, bG, 0, stream>>>(
        WzHi, WzLo, pT_hi, pT_lo, nullptr, nullptr, nullptr, tA, nullptr, nullptr);

    // mm4 (transposed): outT[c][j][h] = act( sum_i zlw[j,i]*act_z[c][h][i] + b_z[j] ) + pT[c][j][h]
    gemm_tn8<false, 2, false><<<gG, bG, 0, stream>>>(
        zlw16, nullptr, tA, nullptr, zlb, pT_hi, pT_lo, nullptr, nullptr, outT);

    // restore [c][h][j]  (f32 -> f32 into d_out)
    transpose_out<<<gT, bT, 0, stream>>>(outT, out);
}

// Round 2
// 1597.476 us; speedup vs baseline: 1.1601x; 1.1163x over previous
//
#include <hip/hip_runtime.h>
#include <hip/hip_bf16.h>

// ---------------------------------------------------------------------------
// CANDY_41077067219071: out = p_out + z_out where
//   t     = Wp_eff @ (x * act(p_mask))          (per channel, 1024^3)
//   p_out = act(act(t) @ p_lin_w^T + b_p)
//   z     = Wzp @ p_out
//   z_out = act(act(z) @ z_lin_w^T + b_z)
// act(v) = clamp(v,-1,1).
// Round-3: round-2 post-mortem showed the split GEMM is LDS-read co-bound:
// 40 ds_read_b128/wave/K-tile (205+ us/CU) vs 199 us MFMA.  Changes:
//   - fragment-reuse phase order: keep all B frags + current A-half live in
//     regs; quadrants (i0-3 x j0-1) -> (i0-3 x j2-3, reuse A) ->
//     (i4-7 x j0-3, reuse B).  Split: 40 -> 24 reads/K-tile (minimum);
//     plain: 20 -> 12.  LDS pipe ~123us << MFMA 199us.
//   - transpose_out fused into mm4 epilogue (LDS 32x258 f32 round-trip,
//     <=2-way bank aliasing both phases): -512MB HBM traffic, -1 kernel.
//   - 3 phases/K-tile: reads+stage-issue | barrier | setprio MFMA | barrier.
//     Counted vmcnt(2) once per K-tile; no __syncthreads in the GEMM.
// Numerics identical (same per-acc K order + 3-product order) -> absmax must
// stay 0.0234375 bit-identical.  OUTPUT IS FLOAT32.
// ---------------------------------------------------------------------------

typedef short bf16x8 __attribute__((ext_vector_type(8)));
typedef float f32x4  __attribute__((ext_vector_type(4)));

__device__ __forceinline__ float actf(float v) { return fminf(1.f, fmaxf(-1.f, v)); }

__device__ __forceinline__ unsigned short f2bf(float f) {
    union { __hip_bfloat16 b; unsigned short u; } cv;
    cv.b = __float2bfloat16(f);
    return cv.u;
}
__device__ __forceinline__ float bf2f(unsigned short u) {
    union { unsigned short u; __hip_bfloat16 b; } cv;
    cv.u = u;
    return __bfloat162float(cv.b);
}

// logical 16B chunk q of row r lives at physical chunk q ^ swz(r)
__device__ __forceinline__ int swz(int r) { return (r ^ (r >> 2)) & 3; }

__device__ __forceinline__ bf16x8 read_frag(const unsigned short* ldsBase, int row, int q) {
    const int pc = q ^ swz(row);
    return *(const bf16x8*)(ldsBase + row * 32 + pc * 8);
}

// EPI 0: O1 = bf16(act(acc))
// EPI 1: v = act(acc + bias[m]); O1 = hi(v), O2 = lo(v)
// EPI 2: v = act(acc + bias[m]) + (Phi+Plo)[off]; out[c][h][j] = v via fused
//        LDS transpose (FLOAT32 store, coalesced over j)
template <bool SPLIT, int EPI, bool TRIL>
__global__ __launch_bounds__(512, 2)
void gemm_tn8(const unsigned short* __restrict__ Ahi,
              const unsigned short* __restrict__ Alo,
              const unsigned short* __restrict__ Bhi,
              const unsigned short* __restrict__ Blo,
              const float* __restrict__ bias,
              const unsigned short* __restrict__ Phi,
              const unsigned short* __restrict__ Plo,
              unsigned short* __restrict__ O1,
              unsigned short* __restrict__ O2,
              float* __restrict__ Of) {
    constexpr int NOPS   = SPLIT ? 4 : 2;   // Ah,Bh[,Al,Bl]
    constexpr int ROUNDS = SPLIT ? 8 : 4;   // global_load_lds issues per K-tile per thread
    // one operand tile = 256 rows x 32 cols bf16 = 8192 elems (16 KiB)
    __shared__ __align__(16) unsigned short lds[NOPS * 2 * 8192];

    const int tid  = threadIdx.x;
    const int lane = tid & 63;
    const int wave = tid >> 6;          // 0..7
    const int wm = wave >> 2;           // 0..1  (M half)
    const int wn = wave & 3;            // 0..3  (N quarter)
    const int q  = lane >> 4;           // k-chunk 0..3
    const int mr = lane & 15;

    const int m0 = blockIdx.y * 256;
    const int n0 = blockIdx.x * 256;
    const size_t cb = (size_t)blockIdx.z << 20;   // per-channel offset (B/C/P only)

    const unsigned short* Bh = Bhi + cb;
    const unsigned short* Bl = SPLIT ? (Blo + cb) : nullptr;

    // stage one 8 KiB round (128 rows) of a 256x32 tile.  LDS dest is
    // wave-uniform base + lane*16 (HW rule); the XOR swizzle is applied on the
    // GLOBAL source address so LDS stays linear (both-sides-or-neither rule).
    auto stage1 = [&](const unsigned short* g, int row0, int k0,
                      unsigned short* base, int rnd) {
        const int ci = rnd * 512 + tid;       // chunk index 0..1023
        const int r  = ci >> 2;               // local row 0..255
        const int pc = ci & 3;                // physical chunk within row
        const int qq = pc ^ swz(r);           // logical chunk fetched from global
        const unsigned short* gsrc = g + ((size_t)(row0 + r) << 10) + k0 + qq * 8;
        unsigned short* ldst = base + (rnd * 512 + wave * 64) * 8;   // wave-uniform
        __builtin_amdgcn_global_load_lds((const __attribute__((address_space(1))) void*)gsrc,
                                         (__attribute__((address_space(3))) void*)ldst,
                                         16, 0, 0);
    };
    // idx is always a compile-time literal at call sites (unrolled contexts)
    auto issueRound = [&](int idx, int k0, int buf) {
        int op, rnd;
        if constexpr (SPLIT) { op = (idx & 1) + ((idx >= 4) ? 2 : 0); rnd = (idx >> 1) & 1; }
        else                 { op = idx & 1; rnd = idx >> 1; }
        const unsigned short* g; int row0;
        switch (op) {
            case 0:  g = Ahi; row0 = m0; break;
            case 1:  g = Bh;  row0 = n0; break;
            case 2:  g = Alo; row0 = m0; break;
            default: g = Bl;  row0 = n0; break;
        }
        stage1(g, row0, k0, lds + (op * 2 + buf) * 8192, rnd);
    };

    f32x4 acc[8][4];
#pragma unroll
    for (int i = 0; i < 8; ++i)
#pragma unroll
        for (int j = 0; j < 4; ++j) acc[i][j] = (f32x4){0.f, 0.f, 0.f, 0.f};

    // tril A: A[h,k]==0 for k>h; rows in this block are <= m0+255
    const int kEnd = TRIL ? ((m0 + 256 < 1024) ? m0 + 256 : 1024) : 1024;
    const int nt = kEnd >> 5;

    // prologue: stage tile 0 into buf 0
#pragma unroll
    for (int idx = 0; idx < ROUNDS; ++idx) issueRound(idx, 0, 0);

    for (int t = 0; t < nt; ++t) {
        const int cur = t & 1;
        const int nxt = cur ^ 1;
        const int k0n = (t + 1) << 5;
        const bool pf = (t + 1) < nt;

        const unsigned short* Ah_ = lds + (0 * 2 + cur) * 8192;
        const unsigned short* Bh_ = lds + (1 * 2 + cur) * 8192;
        const unsigned short* Al_ = SPLIT ? (lds + (2 * 2 + cur) * 8192) : nullptr;
        const unsigned short* Bl_ = SPLIT ? (lds + (3 * 2 + cur) * 8192) : nullptr;

        // ---- K-tile boundary: issue first prefetch rounds of t+1, then wait
        // (counted!) for tile t's loads; barrier makes them visible to all.
        if (pf) {
            issueRound(0, k0n, nxt);
            issueRound(1, k0n, nxt);
            asm volatile("s_waitcnt vmcnt(2)" ::: "memory");
        } else {
            asm volatile("s_waitcnt vmcnt(0)" ::: "memory");
        }
        asm volatile("s_barrier" ::: "memory");

        // ---- phase 0: read A-half0 + B j0-1; MFMA (i0-3) x (j0-1) ----
        bf16x8 aH[4], aL[4], bH[4], bL[4];
#pragma unroll
        for (int i = 0; i < 4; ++i) {
            aH[i] = read_frag(Ah_, wm * 128 + i * 16 + mr, q);
            if constexpr (SPLIT) aL[i] = read_frag(Al_, wm * 128 + i * 16 + mr, q);
        }
#pragma unroll
        for (int j = 0; j < 2; ++j) {
            bH[j] = read_frag(Bh_, wn * 64 + j * 16 + mr, q);
            if constexpr (SPLIT) bL[j] = read_frag(Bl_, wn * 64 + j * 16 + mr, q);
        }
        if (pf) {
            issueRound(2, k0n, nxt);
            issueRound(3, k0n, nxt);
            if constexpr (SPLIT) { issueRound(4, k0n, nxt); issueRound(5, k0n, nxt); }
        }
        asm volatile("s_barrier" ::: "memory");
        __builtin_amdgcn_s_setprio(1);
#pragma unroll
        for (int i = 0; i < 4; ++i)
#pragma unroll
            for (int j = 0; j < 2; ++j) {
                if constexpr (SPLIT) {
                    acc[i][j] = __builtin_amdgcn_mfma_f32_16x16x32_bf16(aL[i], bH[j], acc[i][j], 0, 0, 0);
                    acc[i][j] = __builtin_amdgcn_mfma_f32_16x16x32_bf16(aH[i], bL[j], acc[i][j], 0, 0, 0);
                }
                acc[i][j] = __builtin_amdgcn_mfma_f32_16x16x32_bf16(aH[i], bH[j], acc[i][j], 0, 0, 0);
            }
        __builtin_amdgcn_s_setprio(0);
        __builtin_amdgcn_sched_barrier(0);
        asm volatile("s_barrier" ::: "memory");

        // ---- phase 1: read B j2-3; MFMA (i0-3) x (j2-3), reuse A-half0 ----
#pragma unroll
        for (int j = 0; j < 2; ++j) {
            bH[2 + j] = read_frag(Bh_, wn * 64 + (2 + j) * 16 + mr, q);
            if constexpr (SPLIT) bL[2 + j] = read_frag(Bl_, wn * 64 + (2 + j) * 16 + mr, q);
        }
        if constexpr (SPLIT) {
            if (pf) { issueRound(6, k0n, nxt); issueRound(7, k0n, nxt); }
        }
        asm volatile("s_barrier" ::: "memory");
        __builtin_amdgcn_s_setprio(1);
#pragma unroll
        for (int i = 0; i < 4; ++i)
#pragma unroll
            for (int j = 0; j < 2; ++j) {
                if constexpr (SPLIT) {
                    acc[i][j + 2] = __builtin_amdgcn_mfma_f32_16x16x32_bf16(aL[i], bH[2 + j], acc[i][j + 2], 0, 0, 0);
                    acc[i][j + 2] = __builtin_amdgcn_mfma_f32_16x16x32_bf16(aH[i], bL[2 + j], acc[i][j + 2], 0, 0, 0);
                }
                acc[i][j + 2] = __builtin_amdgcn_mfma_f32_16x16x32_bf16(aH[i], bH[2 + j], acc[i][j + 2], 0, 0, 0);
            }
        __builtin_amdgcn_s_setprio(0);
        __builtin_amdgcn_sched_barrier(0);
        asm volatile("s_barrier" ::: "memory");

        // ---- phase 2: read A-half1; MFMA (i4-7) x (j0-3), reuse all B ----
        bf16x8 cH[4], cL[4];
#pragma unroll
        for (int i = 0; i < 4; ++i) {
            cH[i] = read_frag(Ah_, wm * 128 + 64 + i * 16 + mr, q);
            if constexpr (SPLIT) cL[i] = read_frag(Al_, wm * 128 + 64 + i * 16 + mr, q);
        }
        asm volatile("s_barrier" ::: "memory");
        __builtin_amdgcn_s_setprio(1);
#pragma unroll
        for (int i = 0; i < 4; ++i)
#pragma unroll
            for (int j = 0; j < 4; ++j) {
                if constexpr (SPLIT) {
                    acc[i + 4][j] = __builtin_amdgcn_mfma_f32_16x16x32_bf16(cL[i], bH[j], acc[i + 4][j], 0, 0, 0);
                    acc[i + 4][j] = __builtin_amdgcn_mfma_f32_16x16x32_bf16(cH[i], bL[j], acc[i + 4][j], 0, 0, 0);
                }
                acc[i + 4][j] = __builtin_amdgcn_mfma_f32_16x16x32_bf16(cH[i], bH[j], acc[i + 4][j], 0, 0, 0);
            }
        __builtin_amdgcn_s_setprio(0);
        __builtin_amdgcn_sched_barrier(0);
        asm volatile("s_barrier" ::: "memory");
    }

    // C/D layout (m89/m91-verified): col = lane&15, row = (lane>>4)*4 + reg
    if constexpr (EPI != 2) {
#pragma unroll
        for (int i = 0; i < 8; ++i) {
            const int gmBase = m0 + wm * 128 + i * 16 + q * 4;
#pragma unroll
            for (int j = 0; j < 4; ++j) {
                const int gn = n0 + wn * 64 + j * 16 + mr;
#pragma unroll
                for (int r4 = 0; r4 < 4; ++r4) {
                    const int gm = gmBase + r4;
                    const size_t off = cb + ((size_t)gm << 10) + gn;
                    float v = acc[i][j][r4];
                    if constexpr (EPI == 0) {
                        O1[off] = f2bf(actf(v));
                    } else {
                        v = actf(v + bias[gm]);
                        const unsigned short hi = f2bf(v);
                        O1[off] = hi;
                        O2[off] = f2bf(v - bf2f(hi));
                    }
                }
            }
        }
    } else {
        // Fused transpose epilogue (mm4, SPLIT=false -> 64 KiB staging LDS is
        // free after the final loop barrier).  Per i-strip: 32 j x 256 h f32
        // through LDS [32][258] (stride 258 -> <=2-way bank aliasing on both
        // the scatter-write and the coalesced read).
        float* ldsT = (float*)lds;   // 32*258*4 B = 33 KiB <= 64 KiB
#pragma unroll
        for (int i = 0; i < 8; ++i) {
            const int gmBase = m0 + wm * 128 + i * 16 + q * 4;
#pragma unroll
            for (int j = 0; j < 4; ++j) {
                const int gn = n0 + wn * 64 + j * 16 + mr;
#pragma unroll
                for (int r4 = 0; r4 < 4; ++r4) {
                    const int gm = gmBase + r4;
                    const size_t off = cb + ((size_t)gm << 10) + gn;
                    float v = actf(acc[i][j][r4] + bias[gm]);
                    v += bf2f(Phi[off]) + bf2f(Plo[off]);
                    ldsT[(wm * 16 + q * 4 + r4) * 258 + wn * 64 + j * 16 + mr] = v;
                }
            }
            asm volatile("s_barrier" ::: "memory");
            // drain: 8192 f32 -> out[c][h][j], contiguous 16-float j-runs
#pragma unroll
            for (int s = 0; s < 16; ++s) {
                const int idx = s * 512 + tid;     // 0..8191
                const int hh  = idx >> 5;          // 0..255
                const int jl  = idx & 31;          // ldsT row
                const int jg  = m0 + (jl >> 4) * 128 + i * 16 + (jl & 15);
                const int hg  = n0 + hh;
                Of[cb + ((size_t)hg << 10) + jg] = ldsT[jl * 258 + hh];
            }
            if (i != 7) asm volatile("s_barrier" ::: "memory");
        }
    }
}

// Wp_eff = tril(Wp) with diag -> clamp(diag,0,1) + Wp_diag; split hi/lo.
// Wzp split hi/lo.  p_lin_w / z_lin_w plain bf16 (layout [j][i], K-contig).
__global__ void prep_weights(const float* __restrict__ Wp, const float* __restrict__ Wpd,
                             const float* __restrict__ Wzp,
                             const float* __restrict__ plw, const float* __restrict__ zlw,
                             unsigned short* __restrict__ WpHi, unsigned short* __restrict__ WpLo,
                             unsigned short* __restrict__ WzHi, unsigned short* __restrict__ WzLo,
                             unsigned short* __restrict__ plw16, unsigned short* __restrict__ zlw16) {
    const int idx = blockIdx.x * 256 + threadIdx.x;   // 0..1M-1
    const int h = idx >> 10, k = idx & 1023;
    float v = (k < h) ? Wp[idx] : 0.f;
    if (k == h) v = fminf(1.f, fmaxf(0.f, Wp[idx])) + Wpd[h];
    unsigned short hi = f2bf(v);
    WpHi[idx] = hi; WpLo[idx] = f2bf(v - bf2f(hi));
    const float wz = Wzp[idx];
    hi = f2bf(wz);
    WzHi[idx] = hi; WzLo[idx] = f2bf(wz - bf2f(hi));
    plw16[idx] = f2bf(plw[idx]);
    zlw16[idx] = f2bf(zlw[idx]);
}

// pSetT[c][i][h] = x[c][h][i] * act(p_mask[h][i]), split hi/lo. LDS-tiled transpose.
__global__ void prep_pset(const float* __restrict__ x, const float* __restrict__ pmask,
                          unsigned short* __restrict__ Thi, unsigned short* __restrict__ Tlo) {
    __shared__ float tile[32][33];
    const int tx = threadIdx.x, ty = threadIdx.y;     // 32 x 8
    const int i0 = blockIdx.x * 32, h0 = blockIdx.y * 32;
    const size_t cb = (size_t)blockIdx.z << 20;
#pragma unroll
    for (int s = 0; s < 4; ++s) {
        const int hh = ty + s * 8;
        const size_t gi = ((size_t)(h0 + hh) << 10) + i0 + tx;
        tile[hh][tx] = x[cb + gi] * actf(pmask[gi]);
    }
    __syncthreads();
#pragma unroll
    for (int s = 0; s < 4; ++s) {
        const int ii = ty + s * 8;
        const float v = tile[tx][ii];
        const size_t go = cb + ((size_t)(i0 + ii) << 10) + h0 + tx;
        const unsigned short hi = f2bf(v);
        Thi[go] = hi;
        Tlo[go] = f2bf(v - bf2f(hi));
    }
}

extern "C" void kernel_launch(void* const* d_in, const int* in_sizes, int n_in,
                              void* d_out, int out_size, void* d_ws, size_t ws_size,
                              hipStream_t stream) {
    const float* x     = (const float*)d_in[0];
    const float* pmask = (const float*)d_in[1];
    const float* Wp    = (const float*)d_in[2];
    const float* Wpd   = (const float*)d_in[3];
    const float* Wzp   = (const float*)d_in[4];
    const float* plw   = (const float*)d_in[5];
    const float* plb   = (const float*)d_in[6];
    const float* zlw   = (const float*)d_in[7];
    const float* zlb   = (const float*)d_in[8];
    float* out = (float*)d_out;                     // FLOAT32 output

    char* w = (char*)d_ws;
    const size_t SZ = 134217728ull;                 // 64*1024*1024 bf16 = 128 MiB
    unsigned short* pSetT_hi = (unsigned short*)(w);
    unsigned short* pSetT_lo = (unsigned short*)(w + SZ);
    unsigned short* pT_hi    = (unsigned short*)(w + 2 * SZ);
    unsigned short* pT_lo    = (unsigned short*)(w + 3 * SZ);
    unsigned short* tA       = (unsigned short*)(w + 4 * SZ);  // act_t; reused as act_z
    unsigned short* wts      = (unsigned short*)(w + 5 * SZ);
    unsigned short* WpHi = wts;
    unsigned short* WpLo = wts + 1 * 1048576;
    unsigned short* WzHi = wts + 2 * 1048576;
    unsigned short* WzLo = wts + 3 * 1048576;
    unsigned short* plw16 = wts + 4 * 1048576;
    unsigned short* zlw16 = wts + 5 * 1048576;

    const dim3 gW(4096), bW(256);
    const dim3 gT(32, 32, 64), bT(32, 8);
    const dim3 gG(4, 4, 64), bG(512);

    prep_weights<<<gW, bW, 0, stream>>>(Wp, Wpd, Wzp, plw, zlw,
                                        WpHi, WpLo, WzHi, WzLo, plw16, zlw16);
    prep_pset<<<gT, bT, 0, stream>>>(x, pmask, pSetT_hi, pSetT_lo);

    // mm1: act_t[c][h][i] = act( sum_k Wp_eff[h,k] * pSetT[c][i][k] )   [split, tril]
    gemm_tn8<true, 0, true><<<gG, bG, 0, stream>>>(
        WpHi, WpLo, pSetT_hi, pSetT_lo, nullptr, nullptr, nullptr, tA, nullptr, nullptr);

    // mm2 (transposed): pT[c][j][h] = act( sum_i plw[j,i] * act_t[c][h][i] + b_p[j] ), split store
    gemm_tn8<false, 1, false><<<gG, bG, 0, stream>>>(
        plw16, nullptr, tA, nullptr, plb, nullptr, nullptr, pT_hi, pT_lo, nullptr);

    // mm3: act_z[c][h][i] = act( sum_k Wzp[h,k] * pT[c][i][k] )   [split]
    gemm_tn8<true, 0, false><<<gG, bG, 0, stream>>>(
        WzHi, WzLo, pT_hi, pT_lo, nullptr, nullptr, nullptr, tA, nullptr, nullptr);

    // mm4 (transposed+fused output transpose): out[c][h][j] =
    //   act( sum_i zlw[j,i]*act_z[c][h][i] + b_z[j] ) + pT[c][j][h]
    gemm_tn8<false, 2, false><<<gG, bG, 0, stream>>>(
        zlw16, nullptr, tA, nullptr, zlb, pT_hi, pT_lo, nullptr, nullptr, out);
}